// Round 1
// baseline (638.295 us; speedup 1.0000x reference)
//
#include <hip/hip_runtime.h>
#include <float.h>

#define EPSV 1e-5f

// ---------- helpers ----------
__device__ __forceinline__ int batch_of(int i, const int* __restrict__ offset, int B) {
    int b = 0;
    while (b < B - 1 && i >= offset[b]) ++b;
    return b;
}

// ---------- init: zero counts / stats, init start-min & dmax ----------
__global__ void k_init(int* counts, int KSM, int* startEnc, int* dmax,
                       float* statSum, float* statSq, int B) {
    int tid = blockIdx.x * blockDim.x + threadIdx.x;
    for (int k = tid; k < KSM; k += gridDim.x * blockDim.x) counts[k] = 0;
    if (tid < 64) { statSum[tid] = 0.f; statSq[tid] = 0.f; }
    if (tid < B * 3) startEnc[tid] = 0x7FFFFFFF;   // +inf encoding for non-neg floats
    if (tid < 3) dmax[tid] = 0;                     // v >= 0 always
}

// ---------- per-batch coord min (segment_min) ----------
// chunked: thread handles 4 contiguous points; per-thread min, LDS pre-reduce, 24 global atomics/block
__global__ void k_start(const float* __restrict__ coord, const int* __restrict__ offset,
                        int* startEnc, int N, int B) {
    __shared__ int smin[24];
    int t = threadIdx.x;
    if (t < B * 3) smin[t] = 0x7FFFFFFF;
    __syncthreads();
    int base = (blockIdx.x * blockDim.x + t) * 4;
    int curb = -1;
    int m0 = 0x7FFFFFFF, m1 = 0x7FFFFFFF, m2 = 0x7FFFFFFF;
    for (int r = 0; r < 4; ++r) {
        int i = base + r;
        if (i >= N) break;
        int b = batch_of(i, offset, B);
        if (b != curb) {
            if (curb >= 0) {
                atomicMin(&smin[curb * 3 + 0], m0);
                atomicMin(&smin[curb * 3 + 1], m1);
                atomicMin(&smin[curb * 3 + 2], m2);
            }
            curb = b; m0 = m1 = m2 = 0x7FFFFFFF;
        }
        m0 = min(m0, __float_as_int(coord[(size_t)i * 3 + 0]));
        m1 = min(m1, __float_as_int(coord[(size_t)i * 3 + 1]));
        m2 = min(m2, __float_as_int(coord[(size_t)i * 3 + 2]));
    }
    if (curb >= 0) {
        atomicMin(&smin[curb * 3 + 0], m0);
        atomicMin(&smin[curb * 3 + 1], m1);
        atomicMin(&smin[curb * 3 + 2], m2);
    }
    __syncthreads();
    if (t < B * 3 && smin[t] != 0x7FFFFFFF) atomicMin(&startEnc[t], smin[t]);
}

// ---------- global voxel-extent max ----------
__global__ void k_dims(const float* __restrict__ coord, const int* __restrict__ offset,
                       const int* __restrict__ startEnc, const float* __restrict__ gsP,
                       int* dmax, int N, int B) {
    __shared__ int smax[3];
    int t = threadIdx.x;
    if (t < 3) smax[t] = 0;
    __syncthreads();
    float gs = gsP[0];
    int base = (blockIdx.x * blockDim.x + t) * 4;
    int v0 = 0, v1 = 0, v2 = 0;
    int curb = -1;
    float s0 = 0.f, s1 = 0.f, s2 = 0.f;
    for (int r = 0; r < 4; ++r) {
        int i = base + r;
        if (i >= N) break;
        int b = batch_of(i, offset, B);
        if (b != curb) {
            curb = b;
            s0 = __int_as_float(startEnc[b * 3 + 0]);
            s1 = __int_as_float(startEnc[b * 3 + 1]);
            s2 = __int_as_float(startEnc[b * 3 + 2]);
        }
        v0 = max(v0, (int)floorf((coord[(size_t)i * 3 + 0] - s0) / gs));
        v1 = max(v1, (int)floorf((coord[(size_t)i * 3 + 1] - s1) / gs));
        v2 = max(v2, (int)floorf((coord[(size_t)i * 3 + 2] - s2) / gs));
    }
    atomicMax(&smax[0], v0);
    atomicMax(&smax[1], v1);
    atomicMax(&smax[2], v2);
    __syncthreads();
    if (t < 3) atomicMax(&dmax[t], smax[t]);
}

// ---------- per-point voxel key + histogram ----------
__global__ void k_count(const float* __restrict__ coord, const int* __restrict__ offset,
                        const int* __restrict__ startEnc, const float* __restrict__ gsP,
                        const int* __restrict__ dmax, int* counts, int* vkey,
                        int N, int B, int KSM) {
    int i = blockIdx.x * blockDim.x + threadIdx.x;
    if (i >= N) return;
    float gs = gsP[0];
    int D0 = dmax[0] + 1, D1 = dmax[1] + 1, D2 = dmax[2] + 1;
    int b = batch_of(i, offset, B);
    float s0 = __int_as_float(startEnc[b * 3 + 0]);
    float s1 = __int_as_float(startEnc[b * 3 + 1]);
    float s2 = __int_as_float(startEnc[b * 3 + 2]);
    int vx = (int)floorf((coord[(size_t)i * 3 + 0] - s0) / gs);
    int vy = (int)floorf((coord[(size_t)i * 3 + 1] - s1) / gs);
    int vz = (int)floorf((coord[(size_t)i * 3 + 2] - s2) / gs);
    long long key = (((long long)b * D0 + vx) * D1 + vy) * D2 + vz;
    int k = (int)key;
    if (k < 0) k = 0;
    if (k >= KSM) k = KSM - 1;   // defensive: keep in-bounds
    vkey[i] = k;
    atomicAdd(&counts[k], 1);
}

// ---------- scan pass 1: per-chunk (1024 keys) totals of occupancy and counts ----------
__global__ void k_scan1(const int* __restrict__ counts, int* occPart, int* cntPart, int KSM) {
    __shared__ int so[256], sc[256];
    int t = threadIdx.x;
    int base = blockIdx.x * 1024 + t * 4;
    int o = 0, c = 0;
    for (int r = 0; r < 4; ++r) {
        int k = base + r;
        if (k < KSM) { int cnt = counts[k]; o += (cnt > 0); c += cnt; }
    }
    so[t] = o; sc[t] = c;
    __syncthreads();
    for (int s = 128; s > 0; s >>= 1) {
        if (t < s) { so[t] += so[t + s]; sc[t] += sc[t + s]; }
        __syncthreads();
    }
    if (t == 0) { occPart[blockIdx.x] = so[0]; cntPart[blockIdx.x] = sc[0]; }
}

// ---------- scan pass 2: exclusive scan of block partials (NBLK <= 128), writes M ----------
__global__ void k_scan2(const int* occPart, const int* cntPart,
                        int* occPartEx, int* cntPartEx, int* Mp, int NBLK) {
    __shared__ int so[128], sc[128];
    int t = threadIdx.x;
    int o = (t < NBLK) ? occPart[t] : 0;
    int c = (t < NBLK) ? cntPart[t] : 0;
    so[t] = o; sc[t] = c;
    __syncthreads();
    for (int s = 1; s < 128; s <<= 1) {
        int ao = 0, ac = 0;
        if (t >= s) { ao = so[t - s]; ac = sc[t - s]; }
        __syncthreads();
        so[t] += ao; sc[t] += ac;
        __syncthreads();
    }
    if (t < NBLK) { occPartEx[t] = so[t] - o; cntPartEx[t] = sc[t] - c; }
    if (t == 127) Mp[0] = so[127];   // total clusters
}

// ---------- scan pass 3: full exclusive scans -> clusterIdx (occScan) and bucket starts (cntScan) ----------
__global__ void k_scan3(const int* __restrict__ counts, const int* occPartEx, const int* cntPartEx,
                        int* occScan, int* cntScan, int* cursor, int KSM) {
    __shared__ int so[256], sc[256];
    int t = threadIdx.x;
    int base = blockIdx.x * 1024 + t * 4;
    int o[4], c[4];
    int tO = 0, tC = 0;
    for (int r = 0; r < 4; ++r) {
        int k = base + r;
        int cnt = (k < KSM) ? counts[k] : 0;
        o[r] = (cnt > 0); c[r] = cnt;
        tO += o[r]; tC += c[r];
    }
    so[t] = tO; sc[t] = tC;
    __syncthreads();
    for (int s = 1; s < 256; s <<= 1) {
        int ao = 0, ac = 0;
        if (t >= s) { ao = so[t - s]; ac = sc[t - s]; }
        __syncthreads();
        so[t] += ao; sc[t] += ac;
        __syncthreads();
    }
    int exO = so[t] - tO + occPartEx[blockIdx.x];
    int exC = sc[t] - tC + cntPartEx[blockIdx.x];
    for (int r = 0; r < 4; ++r) {
        int k = base + r;
        if (k < KSM) {
            occScan[k] = exO; cntScan[k] = exC; cursor[k] = 0;
            exO += o[r]; exC += c[r];
        }
    }
}

// ---------- offset_out ----------
__global__ void k_offsets(const int* __restrict__ occScan, const int* __restrict__ dmax,
                          const int* __restrict__ Mp, float* __restrict__ dout, int B) {
    int t = threadIdx.x;
    if (t >= B) return;
    int M = Mp[0];
    long long Dprod = (long long)(dmax[0] + 1) * (dmax[1] + 1) * (dmax[2] + 1);
    int val = (t == B - 1) ? M : occScan[(int)((long long)(t + 1) * Dprod)];
    dout[(size_t)67 * M + t] = (float)val;
}

// ---------- scatter: bucket point lists + write inverse ----------
__global__ void k_scatter(const int* __restrict__ vkey, const int* __restrict__ occScan,
                          const int* __restrict__ cntScan, int* cursor, int* plist,
                          const int* __restrict__ Mp, float* __restrict__ dout, int N, int B) {
    int i = blockIdx.x * blockDim.x + threadIdx.x;
    if (i >= N) return;
    int k = vkey[i];
    int cidx = occScan[k];
    int pos = cntScan[k] + atomicAdd(&cursor[k], 1);
    plist[pos] = i;
    int M = Mp[0];
    dout[(size_t)67 * M + B + i] = (float)cidx;
}

// ---------- cluster kernel: one wave per voxel ----------
// lane c (0..63) owns output channel c, holds W[:,c] in 32 VGPRs.
// Per cluster: gather points, compute raw h rows (LDS broadcast of feat row),
// in-register per-channel max, accumulate global sum/sumsq stats, coord mean.
__launch_bounds__(256)
__global__ void k_cluster(const float* __restrict__ feat, const float* __restrict__ coord,
                          const float* __restrict__ W,
                          const int* __restrict__ counts, const int* __restrict__ occScan,
                          const int* __restrict__ cntScan, const int* __restrict__ plist,
                          const int* __restrict__ Mp,
                          float* __restrict__ dout, float* statSum, float* statSq, int KSM) {
    __shared__ float rowbuf[4][2][32];   // per-wave staging of 2 feat rows
    __shared__ float sred[4][64];        // stats reduction
    const int lane = threadIdx.x & 63;
    const int wid  = threadIdx.x >> 6;
    const int gw = blockIdx.x * 4 + wid;
    const int nw = gridDim.x * 4;
    const int M = Mp[0];

    float Wc[32];
#pragma unroll
    for (int j = 0; j < 32; ++j) Wc[j] = W[j * 64 + lane];

    float sumAcc = 0.f, sqAcc = 0.f;

    for (int k = gw; k < KSM; k += nw) {
        int cnt = counts[k];
        if (cnt == 0) continue;
        int cidx = occScan[k];
        int pstart = cntScan[k];
        float maxv = -FLT_MAX;
        float csum = 0.f;
        for (int i = 0; i < cnt; i += 2) {
            bool has2 = (i + 1) < cnt;
            int p0 = plist[pstart + i];
            int p1 = has2 ? plist[pstart + i + 1] : p0;
            int r = lane >> 5, j = lane & 31;
            int pr = r ? p1 : p0;
            rowbuf[wid][r][j] = feat[(size_t)pr * 32 + j];   // wave-synchronous LDS stage
            float h0 = 0.f, h1 = 0.f;
#pragma unroll
            for (int jj = 0; jj < 32; jj += 4) {
                float4 f0 = *reinterpret_cast<const float4*>(&rowbuf[wid][0][jj]);
                float4 f1 = *reinterpret_cast<const float4*>(&rowbuf[wid][1][jj]);
                h0 += f0.x * Wc[jj] + f0.y * Wc[jj + 1] + f0.z * Wc[jj + 2] + f0.w * Wc[jj + 3];
                h1 += f1.x * Wc[jj] + f1.y * Wc[jj + 1] + f1.z * Wc[jj + 2] + f1.w * Wc[jj + 3];
            }
            maxv = fmaxf(maxv, h0);
            sumAcc += h0; sqAcc += h0 * h0;
            if (has2) { maxv = fmaxf(maxv, h1); sumAcc += h1; sqAcc += h1 * h1; }
            if (lane < 3) {
                csum += coord[(size_t)p0 * 3 + lane];
                if (has2) csum += coord[(size_t)p1 * 3 + lane];
            }
        }
        // raw per-channel max (BN+ReLU applied later; gamma>0 so max commutes)
        dout[(size_t)3 * M + (size_t)cidx * 64 + lane] = maxv;
        if (lane < 3) dout[(size_t)cidx * 3 + lane] = csum / (float)cnt;
    }

    // block-level stats reduction -> 128 global atomics per block
    sred[wid][lane] = sumAcc;
    __syncthreads();
    float s = 0.f;
    if (threadIdx.x < 64)
        s = sred[0][threadIdx.x] + sred[1][threadIdx.x] + sred[2][threadIdx.x] + sred[3][threadIdx.x];
    __syncthreads();
    sred[wid][lane] = sqAcc;
    __syncthreads();
    if (threadIdx.x < 64) {
        float q = sred[0][threadIdx.x] + sred[1][threadIdx.x] + sred[2][threadIdx.x] + sred[3][threadIdx.x];
        atomicAdd(&statSum[threadIdx.x], s);
        atomicAdd(&statSq[threadIdx.x], q);
    }
}

// ---------- BN params from accumulated stats ----------
__global__ void k_bn(const float* statSum, const float* statSq,
                     const float* __restrict__ gamma, const float* __restrict__ beta,
                     float* bnA, float* bnB, int N) {
    int t = threadIdx.x;
    if (t >= 64) return;
    float invN = 1.0f / (float)N;
    float mean = statSum[t] * invN;
    float var = statSq[t] * invN - mean * mean;
    float a = gamma[t] / sqrtf(var + EPSV);
    float b = beta[t] - mean * a;
    bnA[t] = a; bnB[t] = b;
}

// ---------- finalize: apply BN+ReLU to cluster maxima in place ----------
__global__ void k_final(float* __restrict__ dout, const float* __restrict__ bnA,
                        const float* __restrict__ bnB, const int* __restrict__ Mp, int KSM) {
    size_t tid = (size_t)blockIdx.x * blockDim.x + threadIdx.x;
    int M = Mp[0];
    if (tid >= (size_t)M * 64) return;
    int c = (int)(tid & 63);
    float v = dout[(size_t)3 * M + tid];
    dout[(size_t)3 * M + tid] = fmaxf(bnA[c] * v + bnB[c], 0.f);
}

extern "C" void kernel_launch(void* const* d_in, const int* in_sizes, int n_in,
                              void* d_out, int out_size, void* d_ws, size_t ws_size,
                              hipStream_t stream) {
    const float* coord = (const float*)d_in[0];
    const float* feat  = (const float*)d_in[1];
    const int*   offset = (const int*)d_in[2];
    const float* W     = (const float*)d_in[3];
    const float* gamma = (const float*)d_in[4];
    const float* beta  = (const float*)d_in[5];
    const float* gsP   = (const float*)d_in[6];
    float* dout = (float*)d_out;

    const int N = in_sizes[0] / 3;
    const int B = in_sizes[2];
    const int KSM = B * 21 * 21 * 21;              // worst-case keyspace (coords in unit cube)
    const int NBLK = (KSM + 1023) / 1024;          // scan chunks (<=128)

    // workspace layout (int units)
    int* wsI = (int*)d_ws;
    int* startEnc = wsI + 0;            // B*3
    int* dmax     = wsI + 24;           // 3
    int* Mp       = wsI + 27;           // 1
    float* statSum = (float*)(wsI + 32);    // 64
    float* statSq  = (float*)(wsI + 96);    // 64
    float* bnA     = (float*)(wsI + 160);   // 64
    float* bnB     = (float*)(wsI + 224);   // 64
    int* occPart   = wsI + 288;         // 128
    int* cntPart   = wsI + 416;         // 128
    int* occPartEx = wsI + 544;         // 128
    int* cntPartEx = wsI + 672;         // 128
    int* counts  = wsI + 1024;          // KSM
    int* occScan = counts + KSM;        // KSM
    int* cntScan = occScan + KSM;       // KSM
    int* cursor  = cntScan + KSM;       // KSM
    int* vkey    = cursor + KSM;        // N
    int* plist   = vkey + N;            // N

    const int TPB = 256;
    int gInit   = (KSM + TPB - 1) / TPB;
    int gChunk  = (N + 1023) / 1024;
    int gPoint  = (N + TPB - 1) / TPB;
    int gFinal  = (int)(((size_t)KSM * 64 + TPB - 1) / TPB);

    k_init<<<gInit, TPB, 0, stream>>>(counts, KSM, startEnc, dmax, statSum, statSq, B);
    k_start<<<gChunk, TPB, 0, stream>>>(coord, offset, startEnc, N, B);
    k_dims<<<gChunk, TPB, 0, stream>>>(coord, offset, startEnc, gsP, dmax, N, B);
    k_count<<<gPoint, TPB, 0, stream>>>(coord, offset, startEnc, gsP, dmax, counts, vkey, N, B, KSM);
    k_scan1<<<NBLK, TPB, 0, stream>>>(counts, occPart, cntPart, KSM);
    k_scan2<<<1, 128, 0, stream>>>(occPart, cntPart, occPartEx, cntPartEx, Mp, NBLK);
    k_scan3<<<NBLK, TPB, 0, stream>>>(counts, occPartEx, cntPartEx, occScan, cntScan, cursor, KSM);
    k_offsets<<<1, 64, 0, stream>>>(occScan, dmax, Mp, dout, B);
    k_scatter<<<gPoint, TPB, 0, stream>>>(vkey, occScan, cntScan, cursor, plist, Mp, dout, N, B);
    k_cluster<<<1024, TPB, 0, stream>>>(feat, coord, W, counts, occScan, cntScan, plist, Mp,
                                        dout, statSum, statSq, KSM);
    k_bn<<<1, 64, 0, stream>>>(statSum, statSq, gamma, beta, bnA, bnB, N);
    k_final<<<gFinal, TPB, 0, stream>>>(dout, bnA, bnB, Mp, KSM);
}

// Round 2
// 518.073 us; speedup vs baseline: 1.2321x; 1.2321x over previous
//
#include <hip/hip_runtime.h>
#include <float.h>

#define EPSV 1e-5f

// ---------- helpers ----------
__device__ __forceinline__ int batch_of(int i, const int* __restrict__ offset, int B) {
    int b = 0;
    while (b < B - 1 && i >= offset[b]) ++b;
    return b;
}

// ---------- init: zero counts, init start-min & dmax ----------
__global__ void k_init(int* counts, int KSM, int* startEnc, int* dmax, int B) {
    int tid = blockIdx.x * blockDim.x + threadIdx.x;
    for (int k = tid; k < KSM; k += gridDim.x * blockDim.x) counts[k] = 0;
    if (tid < B * 3) startEnc[tid] = 0x7FFFFFFF;   // +inf encoding for non-neg floats
    if (tid < 3) dmax[tid] = 0;                     // v >= 0 always
}

// ---------- per-batch coord min (segment_min) ----------
__global__ void k_start(const float* __restrict__ coord, const int* __restrict__ offset,
                        int* startEnc, int N, int B) {
    __shared__ int smin[24];
    int t = threadIdx.x;
    if (t < B * 3) smin[t] = 0x7FFFFFFF;
    __syncthreads();
    int base = (blockIdx.x * blockDim.x + t) * 4;
    int curb = -1;
    int m0 = 0x7FFFFFFF, m1 = 0x7FFFFFFF, m2 = 0x7FFFFFFF;
    for (int r = 0; r < 4; ++r) {
        int i = base + r;
        if (i >= N) break;
        int b = batch_of(i, offset, B);
        if (b != curb) {
            if (curb >= 0) {
                atomicMin(&smin[curb * 3 + 0], m0);
                atomicMin(&smin[curb * 3 + 1], m1);
                atomicMin(&smin[curb * 3 + 2], m2);
            }
            curb = b; m0 = m1 = m2 = 0x7FFFFFFF;
        }
        m0 = min(m0, __float_as_int(coord[(size_t)i * 3 + 0]));
        m1 = min(m1, __float_as_int(coord[(size_t)i * 3 + 1]));
        m2 = min(m2, __float_as_int(coord[(size_t)i * 3 + 2]));
    }
    if (curb >= 0) {
        atomicMin(&smin[curb * 3 + 0], m0);
        atomicMin(&smin[curb * 3 + 1], m1);
        atomicMin(&smin[curb * 3 + 2], m2);
    }
    __syncthreads();
    if (t < B * 3 && smin[t] != 0x7FFFFFFF) atomicMin(&startEnc[t], smin[t]);
}

// ---------- global voxel-extent max ----------
__global__ void k_dims(const float* __restrict__ coord, const int* __restrict__ offset,
                       const int* __restrict__ startEnc, const float* __restrict__ gsP,
                       int* dmax, int N, int B) {
    __shared__ int smax[3];
    int t = threadIdx.x;
    if (t < 3) smax[t] = 0;
    __syncthreads();
    float gs = gsP[0];
    int base = (blockIdx.x * blockDim.x + t) * 4;
    int v0 = 0, v1 = 0, v2 = 0;
    int curb = -1;
    float s0 = 0.f, s1 = 0.f, s2 = 0.f;
    for (int r = 0; r < 4; ++r) {
        int i = base + r;
        if (i >= N) break;
        int b = batch_of(i, offset, B);
        if (b != curb) {
            curb = b;
            s0 = __int_as_float(startEnc[b * 3 + 0]);
            s1 = __int_as_float(startEnc[b * 3 + 1]);
            s2 = __int_as_float(startEnc[b * 3 + 2]);
        }
        v0 = max(v0, (int)floorf((coord[(size_t)i * 3 + 0] - s0) / gs));
        v1 = max(v1, (int)floorf((coord[(size_t)i * 3 + 1] - s1) / gs));
        v2 = max(v2, (int)floorf((coord[(size_t)i * 3 + 2] - s2) / gs));
    }
    atomicMax(&smax[0], v0);
    atomicMax(&smax[1], v1);
    atomicMax(&smax[2], v2);
    __syncthreads();
    if (t < 3) atomicMax(&dmax[t], smax[t]);
}

// ---------- per-point voxel key + histogram ----------
__global__ void k_count(const float* __restrict__ coord, const int* __restrict__ offset,
                        const int* __restrict__ startEnc, const float* __restrict__ gsP,
                        const int* __restrict__ dmax, int* counts, int* vkey,
                        int N, int B, int KSM) {
    int i = blockIdx.x * blockDim.x + threadIdx.x;
    if (i >= N) return;
    float gs = gsP[0];
    int D0 = dmax[0] + 1, D1 = dmax[1] + 1, D2 = dmax[2] + 1;
    int b = batch_of(i, offset, B);
    float s0 = __int_as_float(startEnc[b * 3 + 0]);
    float s1 = __int_as_float(startEnc[b * 3 + 1]);
    float s2 = __int_as_float(startEnc[b * 3 + 2]);
    int vx = (int)floorf((coord[(size_t)i * 3 + 0] - s0) / gs);
    int vy = (int)floorf((coord[(size_t)i * 3 + 1] - s1) / gs);
    int vz = (int)floorf((coord[(size_t)i * 3 + 2] - s2) / gs);
    long long key = (((long long)b * D0 + vx) * D1 + vy) * D2 + vz;
    int k = (int)key;
    if (k < 0) k = 0;
    if (k >= KSM) k = KSM - 1;   // defensive: keep in-bounds
    vkey[i] = k;
    atomicAdd(&counts[k], 1);
}

// ---------- scan pass 1: per-chunk (1024 keys) totals ----------
__global__ void k_scan1(const int* __restrict__ counts, int* occPart, int* cntPart, int KSM) {
    __shared__ int so[256], sc[256];
    int t = threadIdx.x;
    int base = blockIdx.x * 1024 + t * 4;
    int o = 0, c = 0;
    for (int r = 0; r < 4; ++r) {
        int k = base + r;
        if (k < KSM) { int cnt = counts[k]; o += (cnt > 0); c += cnt; }
    }
    so[t] = o; sc[t] = c;
    __syncthreads();
    for (int s = 128; s > 0; s >>= 1) {
        if (t < s) { so[t] += so[t + s]; sc[t] += sc[t + s]; }
        __syncthreads();
    }
    if (t == 0) { occPart[blockIdx.x] = so[0]; cntPart[blockIdx.x] = sc[0]; }
}

// ---------- scan pass 2: exclusive scan of block partials ----------
__global__ void k_scan2(const int* occPart, const int* cntPart,
                        int* occPartEx, int* cntPartEx, int* Mp, int NBLK) {
    __shared__ int so[128], sc[128];
    int t = threadIdx.x;
    int o = (t < NBLK) ? occPart[t] : 0;
    int c = (t < NBLK) ? cntPart[t] : 0;
    so[t] = o; sc[t] = c;
    __syncthreads();
    for (int s = 1; s < 128; s <<= 1) {
        int ao = 0, ac = 0;
        if (t >= s) { ao = so[t - s]; ac = sc[t - s]; }
        __syncthreads();
        so[t] += ao; sc[t] += ac;
        __syncthreads();
    }
    if (t < NBLK) { occPartEx[t] = so[t] - o; cntPartEx[t] = sc[t] - c; }
    if (t == 127) Mp[0] = so[127];   // total clusters
}

// ---------- scan pass 3: full exclusive scans ----------
__global__ void k_scan3(const int* __restrict__ counts, const int* occPartEx, const int* cntPartEx,
                        int* occScan, int* cntScan, int* cursor, int KSM) {
    __shared__ int so[256], sc[256];
    int t = threadIdx.x;
    int base = blockIdx.x * 1024 + t * 4;
    int o[4], c[4];
    int tO = 0, tC = 0;
    for (int r = 0; r < 4; ++r) {
        int k = base + r;
        int cnt = (k < KSM) ? counts[k] : 0;
        o[r] = (cnt > 0); c[r] = cnt;
        tO += o[r]; tC += c[r];
    }
    so[t] = tO; sc[t] = tC;
    __syncthreads();
    for (int s = 1; s < 256; s <<= 1) {
        int ao = 0, ac = 0;
        if (t >= s) { ao = so[t - s]; ac = sc[t - s]; }
        __syncthreads();
        so[t] += ao; sc[t] += ac;
        __syncthreads();
    }
    int exO = so[t] - tO + occPartEx[blockIdx.x];
    int exC = sc[t] - tC + cntPartEx[blockIdx.x];
    for (int r = 0; r < 4; ++r) {
        int k = base + r;
        if (k < KSM) {
            occScan[k] = exO; cntScan[k] = exC; cursor[k] = 0;
            exO += o[r]; exC += c[r];
        }
    }
}

// ---------- offset_out ----------
__global__ void k_offsets(const int* __restrict__ occScan, const int* __restrict__ dmax,
                          const int* __restrict__ Mp, float* __restrict__ dout, int B) {
    int t = threadIdx.x;
    if (t >= B) return;
    int M = Mp[0];
    long long Dprod = (long long)(dmax[0] + 1) * (dmax[1] + 1) * (dmax[2] + 1);
    int val = (t == B - 1) ? M : occScan[(int)((long long)(t + 1) * Dprod)];
    dout[(size_t)67 * M + t] = (float)val;
}

// ---------- scatter: bucket point lists + write inverse ----------
__global__ void k_scatter(const int* __restrict__ vkey, const int* __restrict__ occScan,
                          const int* __restrict__ cntScan, int* cursor, int* plist,
                          const int* __restrict__ Mp, float* __restrict__ dout, int N, int B) {
    int i = blockIdx.x * blockDim.x + threadIdx.x;
    if (i >= N) return;
    int k = vkey[i];
    int cidx = occScan[k];
    int pos = cntScan[k] + atomicAdd(&cursor[k], 1);
    plist[pos] = i;
    int M = Mp[0];
    dout[(size_t)67 * M + B + i] = (float)cidx;
}

// ---------- cluster kernel: ONE WAVE PER WORKGROUP ----------
// All cluster-chain addresses (counts/occScan/cntScan[k], plist[pstart+i],
// feat+p*32) are block-uniform -> compiler emits s_load; feat rows arrive in
// SGPRs and broadcast into v_fma for free. Zero LDS. lane = output channel,
// W column held in 32 VGPRs. Stats -> per-block partials (no atomics).
__launch_bounds__(64)
__global__ void k_cluster(const float* __restrict__ feat, const float* __restrict__ coord,
                          const float* __restrict__ W,
                          const int* __restrict__ counts, const int* __restrict__ occScan,
                          const int* __restrict__ cntScan, const int* __restrict__ plist,
                          const int* __restrict__ Mp,
                          float* __restrict__ dout, float* __restrict__ statPart, int KSM) {
    const int lane = threadIdx.x;        // 0..63
    const int M = Mp[0];

    float Wc[32];
#pragma unroll
    for (int j = 0; j < 32; ++j) Wc[j] = W[j * 64 + lane];

    float sumAcc = 0.f, sqAcc = 0.f;

    for (int k = blockIdx.x; k < KSM; k += gridDim.x) {
        int cnt = counts[k];                       // uniform -> s_load
        if (cnt == 0) continue;
        int cidx = occScan[k];
        int pstart = cntScan[k];
        float maxv = -FLT_MAX, csum = 0.f;
        int p = plist[pstart];                     // uniform -> s_load
        for (int i = 0; i < cnt; ++i) {
            int pn = (i + 1 < cnt) ? plist[pstart + i + 1] : 0;   // prefetch next index
            const float4* __restrict__ row = reinterpret_cast<const float4*>(feat + (size_t)p * 32);
            float h = 0.f;
#pragma unroll
            for (int q = 0; q < 8; ++q) {
                float4 v = row[q];                 // uniform -> s_load_dwordx4
                h += v.x * Wc[q * 4 + 0] + v.y * Wc[q * 4 + 1]
                   + v.z * Wc[q * 4 + 2] + v.w * Wc[q * 4 + 3];
            }
            maxv = fmaxf(maxv, h);
            sumAcc += h; sqAcc += h * h;
            if (lane < 3) csum += coord[(size_t)p * 3 + lane];
            p = pn;
        }
        // raw per-channel max; BN+ReLU applied in k_final (gamma>0 => max commutes)
        dout[(size_t)3 * M + (size_t)cidx * 64 + lane] = maxv;
        if (lane < 3) dout[(size_t)cidx * 3 + lane] = csum / (float)cnt;
    }

    statPart[(size_t)blockIdx.x * 128 + lane] = sumAcc;
    statPart[(size_t)blockIdx.x * 128 + 64 + lane] = sqAcc;
}

// ---------- reduce stat partials -> BN params (one block per channel) ----------
__global__ void k_statred(const float* __restrict__ statPart,
                          const float* __restrict__ gamma, const float* __restrict__ beta,
                          float* bnA, float* bnB, int NB, int N) {
    __shared__ float s1[256], s2[256];
    int c = blockIdx.x;          // channel
    int t = threadIdx.x;
    float a = 0.f, b = 0.f;
    for (int bb = t; bb < NB; bb += 256) {
        a += statPart[(size_t)bb * 128 + c];
        b += statPart[(size_t)bb * 128 + 64 + c];
    }
    s1[t] = a; s2[t] = b;
    __syncthreads();
    for (int s = 128; s > 0; s >>= 1) {
        if (t < s) { s1[t] += s1[t + s]; s2[t] += s2[t + s]; }
        __syncthreads();
    }
    if (t == 0) {
        float invN = 1.0f / (float)N;
        float mean = s1[0] * invN;
        float var = s2[0] * invN - mean * mean;
        float aa = gamma[c] / sqrtf(var + EPSV);
        bnA[c] = aa;
        bnB[c] = beta[c] - mean * aa;
    }
}

// ---------- finalize: apply BN+ReLU to cluster maxima in place ----------
__global__ void k_final(float* __restrict__ dout, const float* __restrict__ bnA,
                        const float* __restrict__ bnB, const int* __restrict__ Mp) {
    int M = Mp[0];
    size_t total = (size_t)M * 64;
    size_t stride = (size_t)gridDim.x * blockDim.x;
    for (size_t tid = (size_t)blockIdx.x * blockDim.x + threadIdx.x; tid < total; tid += stride) {
        int c = (int)(tid & 63);
        float v = dout[(size_t)3 * M + tid];
        dout[(size_t)3 * M + tid] = fmaxf(bnA[c] * v + bnB[c], 0.f);
    }
}

extern "C" void kernel_launch(void* const* d_in, const int* in_sizes, int n_in,
                              void* d_out, int out_size, void* d_ws, size_t ws_size,
                              hipStream_t stream) {
    const float* coord = (const float*)d_in[0];
    const float* feat  = (const float*)d_in[1];
    const int*   offset = (const int*)d_in[2];
    const float* W     = (const float*)d_in[3];
    const float* gamma = (const float*)d_in[4];
    const float* beta  = (const float*)d_in[5];
    const float* gsP   = (const float*)d_in[6];
    float* dout = (float*)d_out;

    const int N = in_sizes[0] / 3;
    const int B = in_sizes[2];
    const int KSM = B * 21 * 21 * 21;              // worst-case keyspace (coords in unit cube)
    const int NBLK = (KSM + 1023) / 1024;          // scan chunks (<=128)
    const int NBCL = 8192;                         // k_cluster blocks (1 wave each)

    // workspace layout (int units)
    int* wsI = (int*)d_ws;
    int* startEnc = wsI + 0;            // B*3
    int* dmax     = wsI + 24;           // 3
    int* Mp       = wsI + 27;           // 1
    float* bnA     = (float*)(wsI + 32);    // 64
    float* bnB     = (float*)(wsI + 96);    // 64
    int* occPart   = wsI + 160;         // 128
    int* cntPart   = wsI + 288;         // 128
    int* occPartEx = wsI + 416;         // 128
    int* cntPartEx = wsI + 544;         // 128
    int* counts  = wsI + 1024;          // KSM
    int* occScan = counts + KSM;        // KSM
    int* cntScan = occScan + KSM;       // KSM
    int* cursor  = cntScan + KSM;       // KSM
    int* vkey    = cursor + KSM;        // N
    int* plist   = vkey + N;            // N
    float* statPart = (float*)(plist + N);  // NBCL*128

    const int TPB = 256;
    int gInit   = (KSM + TPB - 1) / TPB;
    int gChunk  = (N + 1023) / 1024;
    int gPoint  = (N + TPB - 1) / TPB;

    k_init<<<gInit, TPB, 0, stream>>>(counts, KSM, startEnc, dmax, B);
    k_start<<<gChunk, TPB, 0, stream>>>(coord, offset, startEnc, N, B);
    k_dims<<<gChunk, TPB, 0, stream>>>(coord, offset, startEnc, gsP, dmax, N, B);
    k_count<<<gPoint, TPB, 0, stream>>>(coord, offset, startEnc, gsP, dmax, counts, vkey, N, B, KSM);
    k_scan1<<<NBLK, TPB, 0, stream>>>(counts, occPart, cntPart, KSM);
    k_scan2<<<1, 128, 0, stream>>>(occPart, cntPart, occPartEx, cntPartEx, Mp, NBLK);
    k_scan3<<<NBLK, TPB, 0, stream>>>(counts, occPartEx, cntPartEx, occScan, cntScan, cursor, KSM);
    k_offsets<<<1, 64, 0, stream>>>(occScan, dmax, Mp, dout, B);
    k_scatter<<<gPoint, TPB, 0, stream>>>(vkey, occScan, cntScan, cursor, plist, Mp, dout, N, B);
    k_cluster<<<NBCL, 64, 0, stream>>>(feat, coord, W, counts, occScan, cntScan, plist, Mp,
                                       dout, statPart, KSM);
    k_statred<<<64, 256, 0, stream>>>(statPart, gamma, beta, bnA, bnB, NBCL, N);
    k_final<<<2048, TPB, 0, stream>>>(dout, bnA, bnB, Mp);
}